// Round 1
// baseline (272.230 us; speedup 1.0000x reference)
//
#include <hip/hip_runtime.h>
#include <math.h>

// Problem constants (fixed by the reference)
#define NB   8        // batch
#define LQN  4096     // queries
#define DM   256      // d_model
#define MH   8        // heads
#define PP   4        // points
#define HH   64       // H
#define WW   64       // W
#define DH   32       // head dim = DM/MH
#define NPROJ 96      // 64 offset logits + 32 attn logits

// ---------------------------------------------------------------------------
// Tiled fp32 GEMM, C[M,N] = A[M,K] * B[N,K]^T + bias[N]
// BM=BN=128, BK=8, 256 threads, 8x8 micro-tile per thread.
// M, K assumed multiples of BM/BK; N guarded (for N=96 projection GEMM).
// ---------------------------------------------------------------------------
constexpr int BM = 128, BN = 128, BK = 8, TM = 8, TN = 8;

__global__ __launch_bounds__(256)
void sgemm_nt(const float* __restrict__ A, const float* __restrict__ B,
              const float* __restrict__ bias, float* __restrict__ C,
              int M, int N, int K) {
    __shared__ float As[BK][BM];
    __shared__ float Bs[BK][BN];
    const int t    = threadIdx.x;
    const int brow = blockIdx.x * BM;
    const int bcol = blockIdx.y * BN;
    const int tx   = t & 15;     // 0..15  -> column group (TN=8)
    const int ty   = t >> 4;     // 0..15  -> row group (TM=8)
    const int lrow = t >> 1;     // 0..127 -> staging row
    const int lk   = (t & 1) * 4;

    const float* Aptr = A + (size_t)(brow + lrow) * K + lk;
    const bool   bval = (bcol + lrow) < N;
    const float* Bptr = B + (size_t)(bcol + lrow) * K + lk;

    float acc[TM][TN] = {};

    for (int k0 = 0; k0 < K; k0 += BK) {
        float4 a4 = *(const float4*)(Aptr + k0);
        float4 b4 = bval ? *(const float4*)(Bptr + k0)
                         : make_float4(0.f, 0.f, 0.f, 0.f);
        __syncthreads();
        As[lk + 0][lrow] = a4.x; As[lk + 1][lrow] = a4.y;
        As[lk + 2][lrow] = a4.z; As[lk + 3][lrow] = a4.w;
        Bs[lk + 0][lrow] = b4.x; Bs[lk + 1][lrow] = b4.y;
        Bs[lk + 2][lrow] = b4.z; Bs[lk + 3][lrow] = b4.w;
        __syncthreads();
#pragma unroll
        for (int k = 0; k < BK; ++k) {
            float a[TM], b[TN];
            *(float4*)&a[0] = *(const float4*)&As[k][ty * TM];
            *(float4*)&a[4] = *(const float4*)&As[k][ty * TM + 4];
            *(float4*)&b[0] = *(const float4*)&Bs[k][tx * TN];
            *(float4*)&b[4] = *(const float4*)&Bs[k][tx * TN + 4];
#pragma unroll
            for (int i = 0; i < TM; ++i)
#pragma unroll
                for (int j = 0; j < TN; ++j)
                    acc[i][j] = fmaf(a[i], b[j], acc[i][j]);
        }
    }

#pragma unroll
    for (int i = 0; i < TM; ++i) {
        const int row = brow + ty * TM + i;
#pragma unroll
        for (int j0 = 0; j0 < TN; j0 += 4) {
            const int col = bcol + tx * TN + j0;
            if (col < N) {
                float4 o;
                o.x = acc[i][j0 + 0] + bias[col + 0];
                o.y = acc[i][j0 + 1] + bias[col + 1];
                o.z = acc[i][j0 + 2] + bias[col + 2];
                o.w = acc[i][j0 + 3] + bias[col + 3];
                *(float4*)&C[(size_t)row * N + col] = o;
            }
        }
    }
}

// ---------------------------------------------------------------------------
// Pack Woff(64x256)+Wa(32x256) -> Wcat(96x256), boff(64)+ba(32) -> bcat(96)
// ---------------------------------------------------------------------------
__global__ __launch_bounds__(256)
void pack_proj(const float* __restrict__ Woff, const float* __restrict__ boff,
               const float* __restrict__ Wa,   const float* __restrict__ ba,
               float* __restrict__ Wcat, float* __restrict__ bcat) {
    int i = blockIdx.x * 256 + threadIdx.x;
    if (i < 64 * DM)            Wcat[i] = Woff[i];
    else if (i < NPROJ * DM)    Wcat[i] = Wa[i - 64 * DM];
    if (i < 64)                 bcat[i] = boff[i];
    else if (i < NPROJ)         bcat[i] = ba[i - 64];
}

// ---------------------------------------------------------------------------
// Fused softmax + bilinear sampling.
// One block (256 threads) per query b = n*LQN + lq.
// logits[b][0..63]  = offset logits (m*8 + p*2 + xy)
// logits[b][64..95] = attn logits   (64 + m*4 + p)
// value layout: [n][HW][DM]  (feature j = m*DH + c)
// sampled out:  [b][DM]
// ---------------------------------------------------------------------------
__global__ __launch_bounds__(256)
void sample_kernel(const float* __restrict__ refp,
                   const float* __restrict__ value,
                   const float* __restrict__ logits,
                   float* __restrict__ sampled) {
    const int b = blockIdx.x;          // 0 .. NB*LQN-1
    const int n = b >> 12;             // / LQN
    const int t = threadIdx.x;

    __shared__ float lg[NPROJ];
    __shared__ float xs[MH * PP], ys[MH * PP], aw[MH * PP];

    if (t < NPROJ) lg[t] = logits[(size_t)b * NPROJ + t];
    __syncthreads();

    if (t < MH * PP) {                 // 32 threads: point coordinates
        const int m = t >> 2, p = t & 3;
        const float rx = refp[(size_t)b * 2 + 0];
        const float ry = refp[(size_t)b * 2 + 1];
        const float ox = lg[m * 8 + p * 2 + 0];
        const float oy = lg[m * 8 + p * 2 + 1];
        const float lx = rx + ox * (1.0f / (float)WW);
        const float ly = ry + oy * (1.0f / (float)HH);
        xs[t] = lx * (float)WW - 0.5f;
        ys[t] = ly * (float)HH - 0.5f;
    } else if (t < MH * PP + MH) {     // 8 threads: per-head softmax over p
        const int m = t - MH * PP;
        const float l0 = lg[64 + m * 4 + 0];
        const float l1 = lg[64 + m * 4 + 1];
        const float l2 = lg[64 + m * 4 + 2];
        const float l3 = lg[64 + m * 4 + 3];
        const float mx = fmaxf(fmaxf(l0, l1), fmaxf(l2, l3));
        const float e0 = __expf(l0 - mx), e1 = __expf(l1 - mx);
        const float e2 = __expf(l2 - mx), e3 = __expf(l3 - mx);
        const float inv = 1.0f / (e0 + e1 + e2 + e3);
        aw[m * 4 + 0] = e0 * inv; aw[m * 4 + 1] = e1 * inv;
        aw[m * 4 + 2] = e2 * inv; aw[m * 4 + 3] = e3 * inv;
    }
    __syncthreads();

    const int m = t >> 5;              // head
    const int c = t & 31;              // channel in head
    const float* vbase = value + (size_t)n * (HH * WW) * DM + m * DH + c;

    float acc = 0.f;
#pragma unroll
    for (int p = 0; p < PP; ++p) {
        const float x = xs[m * PP + p];
        const float y = ys[m * PP + p];
        const float w = aw[m * PP + p];
        const float x0f = floorf(x), y0f = floorf(y);
        const int   x0 = (int)x0f,  y0 = (int)y0f;
        const float wx1 = x - x0f,  wy1 = y - y0f;
        const float wx0 = 1.f - wx1, wy0 = 1.f - wy1;

        float s = 0.f;
        const bool xv0 = (x0 >= 0) & (x0 < WW);
        const bool xv1 = (x0 + 1 >= 0) & (x0 + 1 < WW);
        const bool yv0 = (y0 >= 0) & (y0 < HH);
        const bool yv1 = (y0 + 1 >= 0) & (y0 + 1 < HH);
        if (xv0 & yv0) s += wx0 * wy0 * vbase[(size_t)(y0 * WW + x0) * DM];
        if (xv1 & yv0) s += wx1 * wy0 * vbase[(size_t)(y0 * WW + x0 + 1) * DM];
        if (xv0 & yv1) s += wx0 * wy1 * vbase[(size_t)((y0 + 1) * WW + x0) * DM];
        if (xv1 & yv1) s += wx1 * wy1 * vbase[(size_t)((y0 + 1) * WW + x0 + 1) * DM];
        acc = fmaf(w, s, acc);
    }
    sampled[(size_t)b * DM + t] = acc;
}

// ---------------------------------------------------------------------------
extern "C" void kernel_launch(void* const* d_in, const int* in_sizes, int n_in,
                              void* d_out, int out_size, void* d_ws, size_t ws_size,
                              hipStream_t stream) {
    const float* query  = (const float*)d_in[0];   // [8,4096,256]
    const float* refp   = (const float*)d_in[1];   // [8,4096,2]
    const float* inputf = (const float*)d_in[2];   // [8,4096,256]
    // d_in[3]=H, d_in[4]=W (ints, known constants 64)
    const float* Wv   = (const float*)d_in[5];     // [256,256]
    const float* bv   = (const float*)d_in[6];     // [256]
    const float* Woff = (const float*)d_in[7];     // [64,256]
    const float* boff = (const float*)d_in[8];     // [64]
    const float* Wa   = (const float*)d_in[9];     // [32,256]
    const float* ba   = (const float*)d_in[10];    // [32]
    const float* Wo   = (const float*)d_in[11];    // [256,256]
    const float* bo   = (const float*)d_in[12];    // [256]
    float* out = (float*)d_out;

    float* ws      = (float*)d_ws;
    float* value   = ws;                                    // 8,388,608 f
    float* sampled = value   + (size_t)NB * LQN * DM;       // 8,388,608 f
    float* logits  = sampled + (size_t)NB * LQN * DM;       // 3,145,728 f
    float* Wcat    = logits  + (size_t)NB * LQN * NPROJ;    // 24,576 f
    float* bcat    = Wcat    + (size_t)NPROJ * DM;          // 96 f

    const int Mrows = NB * LQN;  // 32768 (= NB*HH*WW as well)

    // 1. pack projection weights
    pack_proj<<<(NPROJ * DM + 255) / 256, 256, 0, stream>>>(Woff, boff, Wa, ba, Wcat, bcat);

    // 2. value = input_flatten @ Wv^T + bv     [32768, 256]
    {
        dim3 g(Mrows / BM, DM / BN);
        sgemm_nt<<<g, 256, 0, stream>>>(inputf, Wv, bv, value, Mrows, DM, DM);
    }

    // 3. logits = query @ Wcat^T + bcat        [32768, 96]
    {
        dim3 g(Mrows / BM, 1);
        sgemm_nt<<<g, 256, 0, stream>>>(query, Wcat, bcat, logits, Mrows, NPROJ, DM);
    }

    // 4. softmax + bilinear sampling -> sampled [32768, 256]
    sample_kernel<<<Mrows, 256, 0, stream>>>(refp, value, logits, sampled);

    // 5. out = sampled @ Wo^T + bo             [32768, 256]
    {
        dim3 g(Mrows / BM, DM / BN);
        sgemm_nt<<<g, 256, 0, stream>>>(sampled, Wo, bo, out, Mrows, DM, DM);
    }
}

// Round 2
// 209.434 us; speedup vs baseline: 1.2998x; 1.2998x over previous
//
#include <hip/hip_runtime.h>
#include <math.h>

// Problem constants (fixed by the reference)
#define NB   8        // batch
#define LQN  4096     // queries
#define DM   256      // d_model
#define MH   8        // heads
#define PP   4        // points
#define HH   64       // H
#define WW   64       // W
#define DH   32       // head dim = DM/MH
#define NPROJ 96      // 64 offset logits + 32 attn logits

// ---------------------------------------------------------------------------
// Tiled fp32 GEMM, C[M,N] = A[M,K] * B[N,K]^T + bias[N]
// BM=BN=128, BK=8, 256 threads, 8x8 micro-tile per thread.
// ---------------------------------------------------------------------------
constexpr int BM = 128, BN = 128, BK = 8, TM = 8, TN = 8;

__global__ __launch_bounds__(256)
void sgemm_nt(const float* __restrict__ A, const float* __restrict__ B,
              const float* __restrict__ bias, float* __restrict__ C,
              int M, int N, int K) {
    __shared__ float As[BK][BM];
    __shared__ float Bs[BK][BN];
    const int t    = threadIdx.x;
    const int brow = blockIdx.x * BM;
    const int bcol = blockIdx.y * BN;
    const int tx   = t & 15;
    const int ty   = t >> 4;
    const int lrow = t >> 1;
    const int lk   = (t & 1) * 4;

    const float* Aptr = A + (size_t)(brow + lrow) * K + lk;
    const bool   bval = (bcol + lrow) < N;
    const float* Bptr = B + (size_t)(bcol + lrow) * K + lk;

    float acc[TM][TN] = {};

    for (int k0 = 0; k0 < K; k0 += BK) {
        float4 a4 = *(const float4*)(Aptr + k0);
        float4 b4 = bval ? *(const float4*)(Bptr + k0)
                         : make_float4(0.f, 0.f, 0.f, 0.f);
        __syncthreads();
        As[lk + 0][lrow] = a4.x; As[lk + 1][lrow] = a4.y;
        As[lk + 2][lrow] = a4.z; As[lk + 3][lrow] = a4.w;
        Bs[lk + 0][lrow] = b4.x; Bs[lk + 1][lrow] = b4.y;
        Bs[lk + 2][lrow] = b4.z; Bs[lk + 3][lrow] = b4.w;
        __syncthreads();
#pragma unroll
        for (int k = 0; k < BK; ++k) {
            float a[TM], b[TN];
            *(float4*)&a[0] = *(const float4*)&As[k][ty * TM];
            *(float4*)&a[4] = *(const float4*)&As[k][ty * TM + 4];
            *(float4*)&b[0] = *(const float4*)&Bs[k][tx * TN];
            *(float4*)&b[4] = *(const float4*)&Bs[k][tx * TN + 4];
#pragma unroll
            for (int i = 0; i < TM; ++i)
#pragma unroll
                for (int j = 0; j < TN; ++j)
                    acc[i][j] = fmaf(a[i], b[j], acc[i][j]);
        }
    }

#pragma unroll
    for (int i = 0; i < TM; ++i) {
        const int row = brow + ty * TM + i;
#pragma unroll
        for (int j0 = 0; j0 < TN; j0 += 4) {
            const int col = bcol + tx * TN + j0;
            if (col < N) {
                float4 o;
                o.x = acc[i][j0 + 0] + bias[col + 0];
                o.y = acc[i][j0 + 1] + bias[col + 1];
                o.z = acc[i][j0 + 2] + bias[col + 2];
                o.w = acc[i][j0 + 3] + bias[col + 3];
                *(float4*)&C[(size_t)row * N + col] = o;
            }
        }
    }
}

// ---------------------------------------------------------------------------
// Pack Woff(64x256)+Wa(32x256) -> Wcat(96x256), boff(64)+ba(32) -> bcat(96)
// ---------------------------------------------------------------------------
__global__ __launch_bounds__(256)
void pack_proj(const float* __restrict__ Woff, const float* __restrict__ boff,
               const float* __restrict__ Wa,   const float* __restrict__ ba,
               float* __restrict__ Wcat, float* __restrict__ bcat) {
    int i = blockIdx.x * 256 + threadIdx.x;
    if (i < 64 * DM)            Wcat[i] = Woff[i];
    else if (i < NPROJ * DM)    Wcat[i] = Wa[i - 64 * DM];
    if (i < 64)                 bcat[i] = boff[i];
    else if (i < NPROJ)         bcat[i] = ba[i - 64];
}

// ---------------------------------------------------------------------------
// Fused softmax + bilinear sampling — one WAVE per query, float4 gathers.
// lane layout for gather: head m = lane>>3, channel-quad c4 = lane&7.
// Point setup: point slot tp = lane&31 (replicated in both wave halves),
// softmax over 4-lane p-groups via shfl_xor; coords broadcast via shfl.
// ---------------------------------------------------------------------------
__device__ __forceinline__ float4 f4axpy(float s, float4 g, float4 a) {
    a.x = fmaf(s, g.x, a.x); a.y = fmaf(s, g.y, a.y);
    a.z = fmaf(s, g.z, a.z); a.w = fmaf(s, g.w, a.w);
    return a;
}

__global__ __launch_bounds__(256)
void sample_kernel(const float* __restrict__ refp,
                   const float* __restrict__ value,
                   const float* __restrict__ logits,
                   float* __restrict__ sampled) {
    const int wid  = threadIdx.x >> 6;            // wave in block, 0..3
    const int b    = blockIdx.x * 4 + wid;        // query index
    const int n    = b >> 12;                     // batch
    const int lane = threadIdx.x & 63;

    // ---- point setup (all lanes; tp replicated across wave halves) ----
    const int tp  = lane & 31;                    // point slot: head pm, point ppt
    const int pm  = tp >> 2, ppt = tp & 3;
    const float* lg = logits + (size_t)b * NPROJ;

    const float rx = refp[(size_t)b * 2 + 0];
    const float ry = refp[(size_t)b * 2 + 1];
    const float ox = lg[pm * 8 + ppt * 2 + 0];
    const float oy = lg[pm * 8 + ppt * 2 + 1];
    const float la = lg[64 + tp];

    // x = ((rx + ox/W)*W) - 0.5 ; same for y
    const float x = fmaf(rx, (float)WW, ox) - 0.5f;
    const float y = fmaf(ry, (float)HH, oy) - 0.5f;

    // softmax over p within the aligned 4-lane group
    float mx = fmaxf(la, __shfl_xor(la, 1));
    mx = fmaxf(mx, __shfl_xor(mx, 2));
    const float e = __expf(la - mx);
    float den = e + __shfl_xor(e, 1);
    den += __shfl_xor(den, 2);
    const float w = e / den;

    // ---- gather: head m, channels [c4*4, c4*4+4) ----
    const int m  = lane >> 3;
    const int c4 = lane & 7;
    const float* vbase = value + (size_t)n * (HH * WW) * DM + m * DH + c4 * 4;

    float4 acc = make_float4(0.f, 0.f, 0.f, 0.f);
#pragma unroll
    for (int p = 0; p < PP; ++p) {
        const int   sl = m * PP + p;              // source lane holding this point
        const float xp = __shfl(x, sl);
        const float yp = __shfl(y, sl);
        const float wp = __shfl(w, sl);

        const float x0f = floorf(xp), y0f = floorf(yp);
        const int   x0 = (int)x0f,   y0 = (int)y0f;
        const float wx1 = xp - x0f,  wy1 = yp - y0f;
        const float wx0 = 1.f - wx1, wy0 = 1.f - wy1;

        const bool xv0 = (unsigned)x0 < WW;
        const bool xv1 = (unsigned)(x0 + 1) < WW;
        const bool yv0 = (unsigned)y0 < HH;
        const bool yv1 = (unsigned)(y0 + 1) < HH;

        float4 s = make_float4(0.f, 0.f, 0.f, 0.f);
        if (xv0 & yv0) s = f4axpy(wx0 * wy0, *(const float4*)(vbase + (size_t)(y0 * WW + x0) * DM), s);
        if (xv1 & yv0) s = f4axpy(wx1 * wy0, *(const float4*)(vbase + (size_t)(y0 * WW + x0 + 1) * DM), s);
        if (xv0 & yv1) s = f4axpy(wx0 * wy1, *(const float4*)(vbase + (size_t)((y0 + 1) * WW + x0) * DM), s);
        if (xv1 & yv1) s = f4axpy(wx1 * wy1, *(const float4*)(vbase + (size_t)((y0 + 1) * WW + x0 + 1) * DM), s);
        acc = f4axpy(wp, s, acc);
    }

    *(float4*)&sampled[(size_t)b * DM + m * DH + c4 * 4] = acc;
}

// ---------------------------------------------------------------------------
extern "C" void kernel_launch(void* const* d_in, const int* in_sizes, int n_in,
                              void* d_out, int out_size, void* d_ws, size_t ws_size,
                              hipStream_t stream) {
    const float* query  = (const float*)d_in[0];   // [8,4096,256]
    const float* refp   = (const float*)d_in[1];   // [8,4096,2]
    const float* inputf = (const float*)d_in[2];   // [8,4096,256]
    const float* Wv   = (const float*)d_in[5];     // [256,256]
    const float* bv   = (const float*)d_in[6];     // [256]
    const float* Woff = (const float*)d_in[7];     // [64,256]
    const float* boff = (const float*)d_in[8];     // [64]
    const float* Wa   = (const float*)d_in[9];     // [32,256]
    const float* ba   = (const float*)d_in[10];    // [32]
    const float* Wo   = (const float*)d_in[11];    // [256,256]
    const float* bo   = (const float*)d_in[12];    // [256]
    float* out = (float*)d_out;

    float* ws      = (float*)d_ws;
    float* value   = ws;                                    // 8,388,608 f
    float* sampled = value   + (size_t)NB * LQN * DM;       // 8,388,608 f
    float* logits  = sampled + (size_t)NB * LQN * DM;       // 3,145,728 f
    float* Wcat    = logits  + (size_t)NB * LQN * NPROJ;    // 24,576 f
    float* bcat    = Wcat    + (size_t)NPROJ * DM;          // 96 f

    const int Mrows = NB * LQN;  // 32768

    // 1. pack projection weights
    pack_proj<<<(NPROJ * DM + 255) / 256, 256, 0, stream>>>(Woff, boff, Wa, ba, Wcat, bcat);

    // 2. value = input_flatten @ Wv^T + bv     [32768, 256]
    {
        dim3 g(Mrows / BM, DM / BN);
        sgemm_nt<<<g, 256, 0, stream>>>(inputf, Wv, bv, value, Mrows, DM, DM);
    }

    // 3. logits = query @ Wcat^T + bcat        [32768, 96]
    {
        dim3 g(Mrows / BM, 1);
        sgemm_nt<<<g, 256, 0, stream>>>(query, Wcat, bcat, logits, Mrows, NPROJ, DM);
    }

    // 4. softmax + bilinear sampling -> sampled [32768, 256], one wave/query
    sample_kernel<<<Mrows / 4, 256, 0, stream>>>(refp, value, logits, sampled);

    // 5. out = sampled @ Wo^T + bo             [32768, 256]
    {
        dim3 g(Mrows / BM, DM / BN);
        sgemm_nt<<<g, 256, 0, stream>>>(sampled, Wo, bo, out, Mrows, DM, DM);
    }
}

// Round 3
// 118.982 us; speedup vs baseline: 2.2880x; 1.7602x over previous
//
#include <hip/hip_runtime.h>
#include <math.h>

// Problem constants (fixed by the reference)
#define NB   8        // batch
#define LQN  4096     // queries
#define DM   256      // d_model
#define MH   8        // heads
#define PP   4        // points
#define HH   64       // H
#define WW   64       // W
#define LG   128      // padded logits row stride (96 real + 32 pad)

typedef __bf16 bf16x8 __attribute__((ext_vector_type(8)));
typedef float  f32x4  __attribute__((ext_vector_type(4)));

__device__ __forceinline__ unsigned short f2bf(float f) {   // RNE fp32 -> bf16 bits
    unsigned u = __float_as_uint(f);
    u += 0x7FFFu + ((u >> 16) & 1u);
    return (unsigned short)(u >> 16);
}
__device__ __forceinline__ float bf2f(unsigned short b) {
    return __uint_as_float((unsigned)b << 16);
}

__device__ __forceinline__ void gl2lds16(const unsigned short* g, unsigned short* l) {
    __builtin_amdgcn_global_load_lds(
        (const __attribute__((address_space(1))) void*)g,
        (__attribute__((address_space(3))) void*)l,
        16, 0, 0);
}

// ---------------------------------------------------------------------------
// bf16 NT GEMM via MFMA: C[M,N] = A[M,K] @ B[N,K]^T + bias[N]
// A,B bf16 (ushort bits), C fp32 or bf16. 128x128 tile, BK=32, 256 thr = 4 waves
// (2x2 of 64x64 per wave), double-buffered LDS, global_load_lds staging.
// M,N multiples of 128; K multiple of 32.
// ---------------------------------------------------------------------------
template <bool OUT_BF16>
__global__ __launch_bounds__(256, 2)
void gemm_bf16_nt(const unsigned short* __restrict__ A,
                  const unsigned short* __restrict__ B,
                  const float* __restrict__ bias, void* __restrict__ Cout,
                  int M, int N, int K) {
    __shared__ unsigned short sA[2][4096];   // [128][32] bf16 per buffer
    __shared__ unsigned short sB[2][4096];

    const int t    = threadIdx.x;
    const int brow = blockIdx.x * 128;
    const int bcol = blockIdx.y * 128;

    const unsigned short* aG = A + (size_t)(brow + (t >> 2)) * K + (t & 3) * 8;
    const unsigned short* bG = B + (size_t)(bcol + (t >> 2)) * K + (t & 3) * 8;
    const size_t rs64 = (size_t)64 * K;

    const int l   = t & 63;
    const int wid = t >> 6;
    const int wr  = wid >> 1, wc = wid & 1;
    const int fr  = l & 15,   kq = l >> 4;

    f32x4 acc[4][4] = {};

    const int NK = K / 32;

    // prologue stage into buf 0
    {
        gl2lds16(aG,        &sA[0][t * 8]);
        gl2lds16(aG + rs64, &sA[0][2048 + t * 8]);
        gl2lds16(bG,        &sB[0][t * 8]);
        gl2lds16(bG + rs64, &sB[0][2048 + t * 8]);
    }

    for (int ks = 0; ks < NK; ++ks) {
        __syncthreads();                       // stage for ks complete
        if (ks + 1 < NK) {                     // prefetch next K-step
            const int nb = (ks & 1) ^ 1;
            const int k0 = (ks + 1) * 32;
            gl2lds16(aG + k0,        &sA[nb][t * 8]);
            gl2lds16(aG + k0 + rs64, &sA[nb][2048 + t * 8]);
            gl2lds16(bG + k0,        &sB[nb][t * 8]);
            gl2lds16(bG + k0 + rs64, &sB[nb][2048 + t * 8]);
        }
        const int buf = ks & 1;
        bf16x8 af[4], bfr[4];
#pragma unroll
        for (int m = 0; m < 4; ++m)
            af[m]  = *(const bf16x8*)&sA[buf][(wr * 64 + m * 16 + fr) * 32 + kq * 8];
#pragma unroll
        for (int n = 0; n < 4; ++n)
            bfr[n] = *(const bf16x8*)&sB[buf][(wc * 64 + n * 16 + fr) * 32 + kq * 8];
#pragma unroll
        for (int m = 0; m < 4; ++m)
#pragma unroll
            for (int n = 0; n < 4; ++n)
                acc[m][n] = __builtin_amdgcn_mfma_f32_16x16x32_bf16(
                    af[m], bfr[n], acc[m][n], 0, 0, 0);
    }

    // epilogue: C[row][col], row = (lane>>4)*4 + j, col = lane&15 within frag
    float*          Cf = (float*)Cout;
    unsigned short* Cb = (unsigned short*)Cout;
#pragma unroll
    for (int n = 0; n < 4; ++n) {
        const int colg = bcol + wc * 64 + n * 16 + fr;
        const float bs = bias[colg];
#pragma unroll
        for (int m = 0; m < 4; ++m) {
            const int rowg = brow + wr * 64 + m * 16 + kq * 4;
#pragma unroll
            for (int j = 0; j < 4; ++j) {
                const float v = acc[m][n][j] + bs;
                if (OUT_BF16) Cb[(size_t)(rowg + j) * N + colg] = f2bf(v);
                else          Cf[(size_t)(rowg + j) * N + colg] = v;
            }
        }
    }
}

// ---------------------------------------------------------------------------
// fp32 [rows x 256] -> split bf16 [rows x 512]: cols 0-255 = hi, 256-511 = lo
// ---------------------------------------------------------------------------
__global__ __launch_bounds__(256)
void split_kernel(const float* __restrict__ src, unsigned short* __restrict__ dst) {
    const int i   = blockIdx.x * 256 + threadIdx.x;  // one float4 per thread
    const int row = i >> 6;
    const int col = (i & 63) * 4;
    const float4 v = *(const float4*)&src[(size_t)row * 256 + col];
    ushort4 h, lo;
    h.x = f2bf(v.x); lo.x = f2bf(v.x - bf2f(h.x));
    h.y = f2bf(v.y); lo.y = f2bf(v.y - bf2f(h.y));
    h.z = f2bf(v.z); lo.z = f2bf(v.z - bf2f(h.z));
    h.w = f2bf(v.w); lo.w = f2bf(v.w - bf2f(h.w));
    *(ushort4*)&dst[(size_t)row * 512 + col]       = h;
    *(ushort4*)&dst[(size_t)row * 512 + 256 + col] = lo;
}

// ---------------------------------------------------------------------------
// Weight prep: duplicate-pack bf16 weights [N][512] = [Wh | Wh], pad Wcat to
// 128 rows with zeros; build bcat (128, fp32).
// ---------------------------------------------------------------------------
__global__ __launch_bounds__(256)
void weight_prep(const float* __restrict__ Wv, const float* __restrict__ Wo,
                 const float* __restrict__ Woff, const float* __restrict__ Wa,
                 const float* __restrict__ boff, const float* __restrict__ ba,
                 unsigned short* __restrict__ Wvd, unsigned short* __restrict__ Wod,
                 unsigned short* __restrict__ Wcatd, float* __restrict__ bcat) {
    const int i = blockIdx.x * 256 + threadIdx.x;
    if (i < 131072) {
        const int n = i >> 9, k = i & 255;
        Wvd[i] = f2bf(Wv[n * 256 + k]);
    } else if (i < 262144) {
        const int j = i - 131072, n = j >> 9, k = j & 255;
        Wod[j] = f2bf(Wo[n * 256 + k]);
    } else if (i < 327680) {
        const int j = i - 262144, n = j >> 9, k = j & 255;
        const float v = (n < 64) ? Woff[n * 256 + k]
                                 : ((n < 96) ? Wa[(n - 64) * 256 + k] : 0.f);
        Wcatd[j] = f2bf(v);
    } else if (i < 327808) {
        const int n = i - 327680;
        bcat[n] = (n < 64) ? boff[n] : ((n < 96) ? ba[n - 64] : 0.f);
    }
}

// ---------------------------------------------------------------------------
// Fused softmax + bilinear sampling — one wave per query; bf16 value/logits;
// emits split-bf16 sampled directly into SPLIT [b][512] (hi | lo).
// ---------------------------------------------------------------------------
__device__ __forceinline__ float4 f4axpy(float s, float4 g, float4 a) {
    a.x = fmaf(s, g.x, a.x); a.y = fmaf(s, g.y, a.y);
    a.z = fmaf(s, g.z, a.z); a.w = fmaf(s, g.w, a.w);
    return a;
}
__device__ __forceinline__ float4 bf4_to_f4(ushort4 u) {
    float4 r;
    r.x = bf2f(u.x); r.y = bf2f(u.y); r.z = bf2f(u.z); r.w = bf2f(u.w);
    return r;
}

__global__ __launch_bounds__(256)
void sample_kernel(const float* __restrict__ refp,
                   const unsigned short* __restrict__ valueB,
                   const unsigned short* __restrict__ logitsB,
                   unsigned short* __restrict__ SPLIT) {
    const int wid  = threadIdx.x >> 6;
    const int b    = blockIdx.x * 4 + wid;
    const int n    = b >> 12;
    const int lane = threadIdx.x & 63;

    const int tp  = lane & 31;
    const int pm  = tp >> 2, ppt = tp & 3;
    const unsigned short* lg = logitsB + (size_t)b * LG;

    const float rx = refp[(size_t)b * 2 + 0];
    const float ry = refp[(size_t)b * 2 + 1];
    const float ox = bf2f(lg[pm * 8 + ppt * 2 + 0]);
    const float oy = bf2f(lg[pm * 8 + ppt * 2 + 1]);
    const float la = bf2f(lg[64 + tp]);

    const float x = fmaf(rx, (float)WW, ox) - 0.5f;
    const float y = fmaf(ry, (float)HH, oy) - 0.5f;

    float mx = fmaxf(la, __shfl_xor(la, 1));
    mx = fmaxf(mx, __shfl_xor(mx, 2));
    const float e = __expf(la - mx);
    float den = e + __shfl_xor(e, 1);
    den += __shfl_xor(den, 2);
    const float w = e / den;

    const int m  = lane >> 3;
    const int c4 = lane & 7;
    const unsigned short* vbase = valueB + (size_t)n * (HH * WW) * DM + m * 32 + c4 * 4;

    float4 acc = make_float4(0.f, 0.f, 0.f, 0.f);
#pragma unroll
    for (int p = 0; p < PP; ++p) {
        const int   sl = m * PP + p;
        const float xp = __shfl(x, sl);
        const float yp = __shfl(y, sl);
        const float wp = __shfl(w, sl);

        const float x0f = floorf(xp), y0f = floorf(yp);
        const int   x0 = (int)x0f,   y0 = (int)y0f;
        const float wx1 = xp - x0f,  wy1 = yp - y0f;
        const float wx0 = 1.f - wx1, wy0 = 1.f - wy1;

        const bool xv0 = (unsigned)x0 < WW;
        const bool xv1 = (unsigned)(x0 + 1) < WW;
        const bool yv0 = (unsigned)y0 < HH;
        const bool yv1 = (unsigned)(y0 + 1) < HH;

        float4 s = make_float4(0.f, 0.f, 0.f, 0.f);
        if (xv0 & yv0) s = f4axpy(wx0 * wy0, bf4_to_f4(*(const ushort4*)(vbase + (size_t)(y0 * WW + x0) * DM)), s);
        if (xv1 & yv0) s = f4axpy(wx1 * wy0, bf4_to_f4(*(const ushort4*)(vbase + (size_t)(y0 * WW + x0 + 1) * DM)), s);
        if (xv0 & yv1) s = f4axpy(wx0 * wy1, bf4_to_f4(*(const ushort4*)(vbase + (size_t)((y0 + 1) * WW + x0) * DM)), s);
        if (xv1 & yv1) s = f4axpy(wx1 * wy1, bf4_to_f4(*(const ushort4*)(vbase + (size_t)((y0 + 1) * WW + x0 + 1) * DM)), s);
        acc = f4axpy(wp, s, acc);
    }

    const int ch = m * 32 + c4 * 4;
    ushort4 h, lo;
    h.x = f2bf(acc.x); lo.x = f2bf(acc.x - bf2f(h.x));
    h.y = f2bf(acc.y); lo.y = f2bf(acc.y - bf2f(h.y));
    h.z = f2bf(acc.z); lo.z = f2bf(acc.z - bf2f(h.z));
    h.w = f2bf(acc.w); lo.w = f2bf(acc.w - bf2f(h.w));
    *(ushort4*)&SPLIT[(size_t)b * 512 + ch]       = h;
    *(ushort4*)&SPLIT[(size_t)b * 512 + 256 + ch] = lo;
}

// ---------------------------------------------------------------------------
extern "C" void kernel_launch(void* const* d_in, const int* in_sizes, int n_in,
                              void* d_out, int out_size, void* d_ws, size_t ws_size,
                              hipStream_t stream) {
    const float* query  = (const float*)d_in[0];   // [8,4096,256]
    const float* refp   = (const float*)d_in[1];   // [8,4096,2]
    const float* inputf = (const float*)d_in[2];   // [8,4096,256]
    const float* Wv   = (const float*)d_in[5];     // [256,256]
    const float* bv   = (const float*)d_in[6];     // [256]
    const float* Woff = (const float*)d_in[7];     // [64,256]
    const float* boff = (const float*)d_in[8];     // [64]
    const float* Wa   = (const float*)d_in[9];     // [32,256]
    const float* ba   = (const float*)d_in[10];    // [32]
    const float* Wo   = (const float*)d_in[11];    // [256,256]
    const float* bo   = (const float*)d_in[12];    // [256]
    float* out = (float*)d_out;

    const int Mrows = NB * LQN;  // 32768

    // workspace layout (ushorts)
    unsigned short* SPLIT   = (unsigned short*)d_ws;        // 32768*512  = 16,777,216
    unsigned short* valueB  = SPLIT   + (size_t)Mrows * 512;   // 32768*256
    unsigned short* logitsB = valueB  + (size_t)Mrows * 256;   // 32768*128
    unsigned short* Wvd     = logitsB + (size_t)Mrows * LG;    // 256*512
    unsigned short* Wod     = Wvd     + 256 * 512;             // 256*512
    unsigned short* Wcatd   = Wod     + 256 * 512;             // 128*512
    float*          bcat    = (float*)(Wcatd + 128 * 512);     // 128

    // 1. weight prep (dup-pack bf16, pad Wcat)
    weight_prep<<<1281, 256, 0, stream>>>(Wv, Wo, Woff, Wa, boff, ba,
                                          Wvd, Wod, Wcatd, bcat);

    // 2. input_flatten -> SPLIT (hi|lo)
    split_kernel<<<Mrows * 64 / 256, 256, 0, stream>>>(inputf, SPLIT);

    // 3. value = input @ Wv^T + bv  (bf16 out)          [32768, 256]
    {
        dim3 g(Mrows / 128, 2);
        gemm_bf16_nt<true><<<g, 256, 0, stream>>>(SPLIT, Wvd, bv, valueB,
                                                  Mrows, DM, 512);
    }

    // 4. query -> SPLIT (hi|lo)   (GEMM above already consumed input-split)
    split_kernel<<<Mrows * 64 / 256, 256, 0, stream>>>(query, SPLIT);

    // 5. logits = query @ Wcat^T + bcat  (bf16 out, padded N=128)
    {
        dim3 g(Mrows / 128, 1);
        gemm_bf16_nt<true><<<g, 256, 0, stream>>>(SPLIT, Wcatd, bcat, logitsB,
                                                  Mrows, LG, 512);
    }

    // 6. softmax + bilinear sampling -> SPLIT (sampled hi|lo)
    sample_kernel<<<Mrows / 4, 256, 0, stream>>>(refp, valueB, logitsB, SPLIT);

    // 7. out = sampled @ Wo^T + bo  (fp32 out)          [32768, 256]
    {
        dim3 g(Mrows / 128, 2);
        gemm_bf16_nt<false><<<g, 256, 0, stream>>>(SPLIT, Wod, bo, out,
                                                   Mrows, DM, 512);
    }
}

// Round 4
// 98.959 us; speedup vs baseline: 2.7509x; 1.2023x over previous
//
#include <hip/hip_runtime.h>
#include <math.h>

// Problem constants (fixed by the reference)
#define NB   8        // batch
#define LQN  4096     // queries
#define DM   256      // d_model
#define MH   8        // heads
#define PP   4        // points
#define HH   64       // H
#define WW   64       // W
#define LG   128      // padded logits row stride (96 real + 32 pad)
#define PW   67       // padded image width/height (x,y in -1..65)
#define PPIX (PW*PW)  // 4489 padded pixels per batch

typedef __bf16 bf16x8 __attribute__((ext_vector_type(8)));
typedef float  f32x4  __attribute__((ext_vector_type(4)));

__device__ __forceinline__ unsigned short f2bf(float f) {   // RNE fp32 -> bf16 bits
    unsigned u = __float_as_uint(f);
    u += 0x7FFFu + ((u >> 16) & 1u);
    return (unsigned short)(u >> 16);
}
__device__ __forceinline__ float bf2f(unsigned short b) {
    return __uint_as_float((unsigned)b << 16);
}

__device__ __forceinline__ void gl2lds16(const unsigned short* g, unsigned short* l) {
    __builtin_amdgcn_global_load_lds(
        (const __attribute__((address_space(1))) void*)g,
        (__attribute__((address_space(3))) void*)l,
        16, 0, 0);
}

// ---------------------------------------------------------------------------
// bf16 NT GEMM via MFMA: C[M,N] = A[M,K] @ B[N,K]^T + bias[N]
// 128x128 tile, BK=32, 256 thr = 4 waves (2x2 of 64x64), double-buffered LDS,
// global_load_lds staging. MODE: 0 = fp32 plain, 1 = bf16 plain,
// 2 = bf16 scattered into padded value image [n][67][67][256].
// ---------------------------------------------------------------------------
template <int MODE>
__global__ __launch_bounds__(256, 2)
void gemm_bf16_nt(const unsigned short* __restrict__ A,
                  const unsigned short* __restrict__ B,
                  const float* __restrict__ bias, void* __restrict__ Cout,
                  int M, int N, int K) {
    __shared__ unsigned short sA[2][4096];   // [128][32] bf16 per buffer
    __shared__ unsigned short sB[2][4096];

    const int t    = threadIdx.x;
    const int brow = blockIdx.x * 128;
    const int bcol = blockIdx.y * 128;

    const unsigned short* aG = A + (size_t)(brow + (t >> 2)) * K + (t & 3) * 8;
    const unsigned short* bG = B + (size_t)(bcol + (t >> 2)) * K + (t & 3) * 8;
    const size_t rs64 = (size_t)64 * K;

    const int l   = t & 63;
    const int wid = t >> 6;
    const int wr  = wid >> 1, wc = wid & 1;
    const int fr  = l & 15,   kq = l >> 4;

    f32x4 acc[4][4] = {};

    const int NK = K / 32;

    // prologue stage into buf 0
    {
        gl2lds16(aG,        &sA[0][t * 8]);
        gl2lds16(aG + rs64, &sA[0][2048 + t * 8]);
        gl2lds16(bG,        &sB[0][t * 8]);
        gl2lds16(bG + rs64, &sB[0][2048 + t * 8]);
    }

    for (int ks = 0; ks < NK; ++ks) {
        __syncthreads();                       // stage for ks complete
        if (ks + 1 < NK) {                     // prefetch next K-step
            const int nb = (ks & 1) ^ 1;
            const int k0 = (ks + 1) * 32;
            gl2lds16(aG + k0,        &sA[nb][t * 8]);
            gl2lds16(aG + k0 + rs64, &sA[nb][2048 + t * 8]);
            gl2lds16(bG + k0,        &sB[nb][t * 8]);
            gl2lds16(bG + k0 + rs64, &sB[nb][2048 + t * 8]);
        }
        const int buf = ks & 1;
        bf16x8 af[4], bfr[4];
#pragma unroll
        for (int m = 0; m < 4; ++m)
            af[m]  = *(const bf16x8*)&sA[buf][(wr * 64 + m * 16 + fr) * 32 + kq * 8];
#pragma unroll
        for (int n = 0; n < 4; ++n)
            bfr[n] = *(const bf16x8*)&sB[buf][(wc * 64 + n * 16 + fr) * 32 + kq * 8];
#pragma unroll
        for (int m = 0; m < 4; ++m)
#pragma unroll
            for (int n = 0; n < 4; ++n)
                acc[m][n] = __builtin_amdgcn_mfma_f32_16x16x32_bf16(
                    af[m], bfr[n], acc[m][n], 0, 0, 0);
    }

    // epilogue: frag (row = (lane>>4)*4 + j, col = lane&15)
    float*          Cf = (float*)Cout;
    unsigned short* Cb = (unsigned short*)Cout;
#pragma unroll
    for (int n = 0; n < 4; ++n) {
        const int colg = bcol + wc * 64 + n * 16 + fr;
        const float bs = bias[colg];
#pragma unroll
        for (int m = 0; m < 4; ++m) {
            const int rowg = brow + wr * 64 + m * 16 + kq * 4;
#pragma unroll
            for (int j = 0; j < 4; ++j) {
                const float v = acc[m][n][j] + bs;
                const int row = rowg + j;
                if (MODE == 0) {
                    Cf[(size_t)row * N + colg] = v;
                } else if (MODE == 1) {
                    Cb[(size_t)row * N + colg] = f2bf(v);
                } else {
                    // padded value image: row = n*4096 + y*64 + x
                    const int nb_ = row >> 12;
                    const int pix = row & 4095;
                    const int y   = pix >> 6, x = pix & 63;
                    const size_t addr =
                        ((size_t)nb_ * PPIX + (size_t)(y + 1) * PW + (x + 1)) * DM + colg;
                    Cb[addr] = f2bf(v);
                }
            }
        }
    }
}

// ---------------------------------------------------------------------------
// Zero the padded value buffer (borders stay zero; GEMM fills interior).
// ---------------------------------------------------------------------------
__global__ __launch_bounds__(256)
void zero_kernel(unsigned short* __restrict__ p) {
    const size_t i = ((size_t)blockIdx.x * 256 + threadIdx.x) * 8;
    *(ulonglong2*)&p[i] = make_ulonglong2(0ull, 0ull);   // 16 B of zeros
}

// ---------------------------------------------------------------------------
// Fused split: input_flatten -> SPLIT_A (hi|lo, 512 wide);
//              query         -> QH (hi only, 256 wide)
// ---------------------------------------------------------------------------
__global__ __launch_bounds__(256)
void split_fused(const float* __restrict__ input, const float* __restrict__ query,
                 unsigned short* __restrict__ SPLIT_A, unsigned short* __restrict__ QH) {
    const int i = blockIdx.x * 256 + threadIdx.x;     // one float4 per thread
    if (i < NB * LQN * 64) {
        const int row = i >> 6;
        const int col = (i & 63) * 4;
        const float4 v = *(const float4*)&input[(size_t)row * 256 + col];
        ushort4 h, lo;
        h.x = f2bf(v.x); lo.x = f2bf(v.x - bf2f(h.x));
        h.y = f2bf(v.y); lo.y = f2bf(v.y - bf2f(h.y));
        h.z = f2bf(v.z); lo.z = f2bf(v.z - bf2f(h.z));
        h.w = f2bf(v.w); lo.w = f2bf(v.w - bf2f(h.w));
        *(ushort4*)&SPLIT_A[(size_t)row * 512 + col]       = h;
        *(ushort4*)&SPLIT_A[(size_t)row * 512 + 256 + col] = lo;
    } else {
        const int j   = i - NB * LQN * 64;
        const int row = j >> 6;
        const int col = (j & 63) * 4;
        const float4 v = *(const float4*)&query[(size_t)row * 256 + col];
        ushort4 h;
        h.x = f2bf(v.x); h.y = f2bf(v.y); h.z = f2bf(v.z); h.w = f2bf(v.w);
        *(ushort4*)&QH[(size_t)row * 256 + col] = h;
    }
}

// ---------------------------------------------------------------------------
// Weight prep: Wvd/Wod = dup-packed bf16 [256][512] = [Wh|Wh];
// Wcatd = bf16 [128][256] (rows 96-127 zero); bcat fp32 [128].
// ---------------------------------------------------------------------------
__global__ __launch_bounds__(256)
void weight_prep(const float* __restrict__ Wv, const float* __restrict__ Wo,
                 const float* __restrict__ Woff, const float* __restrict__ Wa,
                 const float* __restrict__ boff, const float* __restrict__ ba,
                 unsigned short* __restrict__ Wvd, unsigned short* __restrict__ Wod,
                 unsigned short* __restrict__ Wcatd, float* __restrict__ bcat) {
    const int i = blockIdx.x * 256 + threadIdx.x;
    if (i < 131072) {
        const int n = i >> 9, k = i & 255;
        Wvd[i] = f2bf(Wv[n * 256 + k]);
    } else if (i < 262144) {
        const int j = i - 131072, n = j >> 9, k = j & 255;
        Wod[j] = f2bf(Wo[n * 256 + k]);
    } else if (i < 294912) {
        const int j = i - 262144, n = j >> 8, k = j & 255;
        const float v = (n < 64) ? Woff[n * 256 + k]
                                 : ((n < 96) ? Wa[(n - 64) * 256 + k] : 0.f);
        Wcatd[j] = f2bf(v);
    } else if (i < 295040) {
        const int n = i - 294912;
        bcat[n] = (n < 64) ? boff[n] : ((n < 96) ? ba[n - 64] : 0.f);
    }
}

// ---------------------------------------------------------------------------
// Fused softmax + bilinear sampling — one wave per query, branch-free gathers
// from the zero-padded value image; XCD-swizzled so XCD k handles batch k.
// Emits split-bf16 sampled (hi|lo) into SPLIT_S [b][512].
// ---------------------------------------------------------------------------
__device__ __forceinline__ float4 f4axpy(float s, float4 g, float4 a) {
    a.x = fmaf(s, g.x, a.x); a.y = fmaf(s, g.y, a.y);
    a.z = fmaf(s, g.z, a.z); a.w = fmaf(s, g.w, a.w);
    return a;
}
__device__ __forceinline__ float4 bf4_to_f4(ushort4 u) {
    float4 r;
    r.x = bf2f(u.x); r.y = bf2f(u.y); r.z = bf2f(u.z); r.w = bf2f(u.w);
    return r;
}

__global__ __launch_bounds__(256)
void sample_kernel(const float* __restrict__ refp,
                   const unsigned short* __restrict__ valueP,
                   const unsigned short* __restrict__ logitsB,
                   unsigned short* __restrict__ SPLIT_S) {
    // XCD swizzle: 8192 blocks, round-robin XCD = blockIdx%8; give XCD k batch k.
    const int vb   = (blockIdx.x & 7) * 1024 + (blockIdx.x >> 3);
    const int wid  = threadIdx.x >> 6;
    const int b    = vb * 4 + wid;
    const int n    = b >> 12;
    const int lane = threadIdx.x & 63;

    const int tp  = lane & 31;                 // point slot (replicated halves)
    const int pm  = tp >> 2, ppt = tp & 3;
    const unsigned short* lg = logitsB + (size_t)b * LG;

    const float rx = refp[(size_t)b * 2 + 0];
    const float ry = refp[(size_t)b * 2 + 1];
    const float ox = bf2f(lg[pm * 8 + ppt * 2 + 0]);
    const float oy = bf2f(lg[pm * 8 + ppt * 2 + 1]);
    const float la = bf2f(lg[64 + tp]);

    // clamp to [-1, 64]: identical to zero-pad + validity masks
    const float x = fminf(fmaxf(fmaf(rx, (float)WW, ox) - 0.5f, -1.0f), 64.0f);
    const float y = fminf(fmaxf(fmaf(ry, (float)HH, oy) - 0.5f, -1.0f), 64.0f);

    float mx = fmaxf(la, __shfl_xor(la, 1));
    mx = fmaxf(mx, __shfl_xor(mx, 2));
    const float e = __expf(la - mx);
    float den = e + __shfl_xor(e, 1);
    den += __shfl_xor(den, 2);
    const float w = e / den;

    const int m  = lane >> 3;
    const int c4 = lane & 7;
    const unsigned short* vbase = valueP + (size_t)n * (PPIX * DM) + m * 32 + c4 * 4;

    float4 acc = make_float4(0.f, 0.f, 0.f, 0.f);
#pragma unroll
    for (int p = 0; p < PP; ++p) {
        const int   sl = m * PP + p;
        const float xp = __shfl(x, sl);
        const float yp = __shfl(y, sl);
        const float wp = __shfl(w, sl);

        const float x0f = floorf(xp), y0f = floorf(yp);
        const int   x0 = (int)x0f,   y0 = (int)y0f;
        const float wx1 = xp - x0f,  wy1 = yp - y0f;
        const float wx0 = 1.f - wx1, wy0 = 1.f - wy1;

        const float w00 = wp * wx0 * wy0, w01 = wp * wx1 * wy0;
        const float w10 = wp * wx0 * wy1, w11 = wp * wx1 * wy1;

        const int idx = (y0 + 1) * PW + (x0 + 1);   // padded pixel index
        const unsigned short* p00 = vbase + (size_t)idx * DM;

        const ushort4 g00 = *(const ushort4*)(p00);
        const ushort4 g01 = *(const ushort4*)(p00 + DM);
        const ushort4 g10 = *(const ushort4*)(p00 + PW * DM);
        const ushort4 g11 = *(const ushort4*)(p00 + (PW + 1) * DM);

        acc = f4axpy(w00, bf4_to_f4(g00), acc);
        acc = f4axpy(w01, bf4_to_f4(g01), acc);
        acc = f4axpy(w10, bf4_to_f4(g10), acc);
        acc = f4axpy(w11, bf4_to_f4(g11), acc);
    }

    const int ch = m * 32 + c4 * 4;
    ushort4 h, lo;
    h.x = f2bf(acc.x); lo.x = f2bf(acc.x - bf2f(h.x));
    h.y = f2bf(acc.y); lo.y = f2bf(acc.y - bf2f(h.y));
    h.z = f2bf(acc.z); lo.z = f2bf(acc.z - bf2f(h.z));
    h.w = f2bf(acc.w); lo.w = f2bf(acc.w - bf2f(h.w));
    *(ushort4*)&SPLIT_S[(size_t)b * 512 + ch]       = h;
    *(ushort4*)&SPLIT_S[(size_t)b * 512 + 256 + ch] = lo;
}

// ---------------------------------------------------------------------------
extern "C" void kernel_launch(void* const* d_in, const int* in_sizes, int n_in,
                              void* d_out, int out_size, void* d_ws, size_t ws_size,
                              hipStream_t stream) {
    const float* query  = (const float*)d_in[0];   // [8,4096,256]
    const float* refp   = (const float*)d_in[1];   // [8,4096,2]
    const float* inputf = (const float*)d_in[2];   // [8,4096,256]
    const float* Wv   = (const float*)d_in[5];     // [256,256]
    const float* bv   = (const float*)d_in[6];     // [256]
    const float* Woff = (const float*)d_in[7];     // [64,256]
    const float* boff = (const float*)d_in[8];     // [64]
    const float* Wa   = (const float*)d_in[9];     // [32,256]
    const float* ba   = (const float*)d_in[10];    // [32]
    const float* Wo   = (const float*)d_in[11];    // [256,256]
    const float* bo   = (const float*)d_in[12];    // [256]
    float* out = (float*)d_out;

    const int Mrows = NB * LQN;  // 32768

    // workspace layout (ushort units); ws ~268 MB, we use ~111 MB
    unsigned short* SPLIT_A = (unsigned short*)d_ws;             // 16,777,216
    unsigned short* SPLIT_S = SPLIT_A + (size_t)Mrows * 512;     // 16,777,216
    unsigned short* QH      = SPLIT_S + (size_t)Mrows * 512;     //  8,388,608
    unsigned short* valueP  = QH      + (size_t)Mrows * 256;     //  9,193,472
    unsigned short* logitsB = valueP  + (size_t)NB * PPIX * DM;  //  4,194,304
    unsigned short* Wvd     = logitsB + (size_t)Mrows * LG;      //    131,072
    unsigned short* Wod     = Wvd     + 256 * 512;               //    131,072
    unsigned short* Wcatd   = Wod     + 256 * 512;               //     32,768
    float*          bcat    = (float*)(Wcatd + 128 * 256);       //        128

    // 1. weight prep
    weight_prep<<<1153, 256, 0, stream>>>(Wv, Wo, Woff, Wa, boff, ba,
                                          Wvd, Wod, Wcatd, bcat);

    // 2. zero padded value image (8*4489*256 ushorts = 4489 blocks * 256 thr * 8)
    zero_kernel<<<NB * PPIX * DM / (256 * 8), 256, 0, stream>>>(valueP);

    // 3. fused split: input -> SPLIT_A (hi|lo); query -> QH (hi)
    split_fused<<<Mrows * 64 * 2 / 256, 256, 0, stream>>>(inputf, query, SPLIT_A, QH);

    // 4. value = input @ Wv^T + bv  -> padded bf16 image   [K=512]
    {
        dim3 g(Mrows / 128, 2);
        gemm_bf16_nt<2><<<g, 256, 0, stream>>>(SPLIT_A, Wvd, bv, valueP,
                                               Mrows, DM, 512);
    }

    // 5. logits = query @ Wcat^T + bcat (hi-only, K=256, N=128, bf16 out)
    {
        dim3 g(Mrows / 128, 1);
        gemm_bf16_nt<1><<<g, 256, 0, stream>>>(QH, Wcatd, bcat, logitsB,
                                               Mrows, LG, 256);
    }

    // 6. softmax + bilinear sampling -> SPLIT_S (hi|lo)
    sample_kernel<<<Mrows / 4, 256, 0, stream>>>(refp, valueP, logitsB, SPLIT_S);

    // 7. out = sampled @ Wo^T + bo  (fp32 out)             [K=512]
    {
        dim3 g(Mrows / 128, 2);
        gemm_bf16_nt<0><<<g, 256, 0, stream>>>(SPLIT_S, Wod, bo, out,
                                               Mrows, DM, 512);
    }
}

// Round 5
// 80.266 us; speedup vs baseline: 3.3916x; 1.2329x over previous
//
#include <hip/hip_runtime.h>
#include <math.h>

// Problem constants (fixed by the reference)
#define NB   8        // batch
#define LQN  4096     // queries
#define DM   256      // d_model
#define MH   8        // heads
#define PP   4        // points
#define HH   64       // H
#define WW   64       // W
#define LG   128      // padded logits row stride (96 real + 32 pad)
#define PW   67       // padded image width/height (x,y in -1..65)
#define PPIX (PW*PW)  // 4489 padded pixels per batch
#define ASTR 40       // LDS A-plane row stride in ushorts (32 + 8 pad -> 80B)

typedef __bf16 bf16x8 __attribute__((ext_vector_type(8)));
typedef float  f32x4  __attribute__((ext_vector_type(4)));
typedef unsigned short us8 __attribute__((ext_vector_type(8)));

__device__ __forceinline__ unsigned short f2bf(float f) {   // RNE fp32 -> bf16 bits
    unsigned u = __float_as_uint(f);
    u += 0x7FFFu + ((u >> 16) & 1u);
    return (unsigned short)(u >> 16);
}
__device__ __forceinline__ float bf2f(unsigned short b) {
    return __uint_as_float((unsigned)b << 16);
}

__device__ __forceinline__ void gl2lds16(const unsigned short* g, unsigned short* l) {
    __builtin_amdgcn_global_load_lds(
        (const __attribute__((address_space(1))) void*)g,
        (__attribute__((address_space(3))) void*)l,
        16, 0, 0);
}

// ---------------------------------------------------------------------------
// Fused-convert GEMM: C[M,N] = A_f32[M,256] @ B_bf16[N,256]^T + bias[N]
// A is fp32 in HBM; staged to LDS as bf16 hi (+ optional lo) planes via
// registers (global->reg->cvt->ds_write). Per K-step: acc += Ah*B (+ Al*B).
// 128x128 tile, BK=32, 256 thr = 4 waves (2x2 of 64x64), double-buffered.
// MODE: 1 = bf16 plain store, 2 = bf16 scatter into padded value image.
// ---------------------------------------------------------------------------
template <int MODE, bool USE_LO>
__global__ __launch_bounds__(256, 2)
void gemm_f32a(const float* __restrict__ A, const unsigned short* __restrict__ B,
               const float* __restrict__ bias, void* __restrict__ Cout,
               int M, int N) {
    constexpr int K = 256;
    __shared__ unsigned short sAh[2][128 * ASTR];
    __shared__ unsigned short sAl[2][128 * ASTR];
    __shared__ unsigned short sB [2][4096];

    const int t    = threadIdx.x;
    const int brow = blockIdx.x * 128;
    const int bcol = blockIdx.y * 128;

    // A staging map: thread t -> row ar = t>>1, cols [(t&1)*16, +16)
    const int ar  = t >> 1;
    const int as_ = (t & 1) * 16;
    const float* aG = A + (size_t)(brow + ar) * K + as_;
    const int abase = ar * ASTR + as_;

    // B staging map (gl2lds, lane-linear dest): rows t>>2 and +64, cols (t&3)*8
    const unsigned short* bG = B + (size_t)(bcol + (t >> 2)) * K + (t & 3) * 8;
    const size_t brs64 = (size_t)64 * K;

    const int l   = t & 63;
    const int wid = t >> 6;
    const int wr  = wid >> 1, wc = wid & 1;
    const int fr  = l & 15,   kq = l >> 4;

    f32x4 acc[4][4] = {};
    float4 va[4];

#define LOAD_A(k0)                                                     \
    {  _Pragma("unroll")                                               \
       for (int j = 0; j < 4; ++j)                                     \
           va[j] = *(const float4*)(aG + (k0) + j * 4); }

#define STAGE_B(buf, k0)                                               \
    {  gl2lds16(bG + (k0),         &sB[buf][t * 8]);                   \
       gl2lds16(bG + (k0) + brs64, &sB[buf][2048 + t * 8]); }

#define STAGE_A(buf)                                                   \
    {  _Pragma("unroll")                                               \
       for (int g = 0; g < 2; ++g) {                                   \
           us8 Hv, Lv;                                                 \
           _Pragma("unroll")                                           \
           for (int j = 0; j < 2; ++j) {                               \
               const float4 v = va[g * 2 + j];                         \
               const unsigned short hx = f2bf(v.x), hy = f2bf(v.y);    \
               const unsigned short hz = f2bf(v.z), hw = f2bf(v.w);    \
               Hv[j*4+0] = hx; Hv[j*4+1] = hy;                         \
               Hv[j*4+2] = hz; Hv[j*4+3] = hw;                         \
               if (USE_LO) {                                           \
                   Lv[j*4+0] = f2bf(v.x - bf2f(hx));                   \
                   Lv[j*4+1] = f2bf(v.y - bf2f(hy));                   \
                   Lv[j*4+2] = f2bf(v.z - bf2f(hz));                   \
                   Lv[j*4+3] = f2bf(v.w - bf2f(hw));                   \
               }                                                       \
           }                                                           \
           *(us8*)&sAh[buf][abase + g * 8] = Hv;                       \
           if (USE_LO) *(us8*)&sAl[buf][abase + g * 8] = Lv;           \
       } }

    // prologue: stage step 0 into buf 0
    LOAD_A(0);
    STAGE_B(0, 0);
    STAGE_A(0);

    for (int ks = 0; ks < K / 32; ++ks) {
        __syncthreads();                       // buf cur fully staged
        const int cur = ks & 1, nxt = cur ^ 1;
        const bool more = (ks + 1 < K / 32);
        if (more) {                            // issue next-step loads early
            LOAD_A((ks + 1) * 32);
            STAGE_B(nxt, (ks + 1) * 32);
        }

        bf16x8 ah[4], al_[4], bf_[4];
#pragma unroll
        for (int m = 0; m < 4; ++m)
            ah[m] = *(const bf16x8*)&sAh[cur][(wr * 64 + m * 16 + fr) * ASTR + kq * 8];
        if (USE_LO) {
#pragma unroll
            for (int m = 0; m < 4; ++m)
                al_[m] = *(const bf16x8*)&sAl[cur][(wr * 64 + m * 16 + fr) * ASTR + kq * 8];
        }
#pragma unroll
        for (int n = 0; n < 4; ++n)
            bf_[n] = *(const bf16x8*)&sB[cur][(wc * 64 + n * 16 + fr) * 32 + kq * 8];

#pragma unroll
        for (int m = 0; m < 4; ++m)
#pragma unroll
            for (int n = 0; n < 4; ++n) {
                acc[m][n] = __builtin_amdgcn_mfma_f32_16x16x32_bf16(
                    ah[m], bf_[n], acc[m][n], 0, 0, 0);
                if (USE_LO)
                    acc[m][n] = __builtin_amdgcn_mfma_f32_16x16x32_bf16(
                        al_[m], bf_[n], acc[m][n], 0, 0, 0);
            }

        if (more) STAGE_A(nxt);                // convert + write after MFMAs
    }
#undef LOAD_A
#undef STAGE_B
#undef STAGE_A

    // epilogue: frag (row = (lane>>4)*4 + j, col = lane&15)
    unsigned short* Cb = (unsigned short*)Cout;
#pragma unroll
    for (int n = 0; n < 4; ++n) {
        const int colg = bcol + wc * 64 + n * 16 + fr;
        const float bs = bias[colg];
#pragma unroll
        for (int m = 0; m < 4; ++m) {
            const int rowg = brow + wr * 64 + m * 16 + kq * 4;
#pragma unroll
            for (int j = 0; j < 4; ++j) {
                const float v = acc[m][n][j] + bs;
                const int row = rowg + j;
                if (MODE == 1) {
                    Cb[(size_t)row * N + colg] = f2bf(v);
                } else {
                    const int nb_ = row >> 12;
                    const int pix = row & 4095;
                    const int y   = pix >> 6, x = pix & 63;
                    const size_t addr =
                        ((size_t)nb_ * PPIX + (size_t)(y + 1) * PW + (x + 1)) * DM + colg;
                    Cb[addr] = f2bf(v);
                }
            }
        }
    }
}

// ---------------------------------------------------------------------------
// bf16 NT GEMM (gl2lds staging), fp32 out: used for out = sampled_split @ WoD^T
// ---------------------------------------------------------------------------
__global__ __launch_bounds__(256, 2)
void gemm_bf16_nt(const unsigned short* __restrict__ A,
                  const unsigned short* __restrict__ B,
                  const float* __restrict__ bias, float* __restrict__ C,
                  int M, int N, int K) {
    __shared__ unsigned short sA[2][4096];
    __shared__ unsigned short sB[2][4096];

    const int t    = threadIdx.x;
    const int brow = blockIdx.x * 128;
    const int bcol = blockIdx.y * 128;

    const unsigned short* aG = A + (size_t)(brow + (t >> 2)) * K + (t & 3) * 8;
    const unsigned short* bG = B + (size_t)(bcol + (t >> 2)) * K + (t & 3) * 8;
    const size_t rs64 = (size_t)64 * K;

    const int l   = t & 63;
    const int wid = t >> 6;
    const int wr  = wid >> 1, wc = wid & 1;
    const int fr  = l & 15,   kq = l >> 4;

    f32x4 acc[4][4] = {};
    const int NK = K / 32;

    gl2lds16(aG,        &sA[0][t * 8]);
    gl2lds16(aG + rs64, &sA[0][2048 + t * 8]);
    gl2lds16(bG,        &sB[0][t * 8]);
    gl2lds16(bG + rs64, &sB[0][2048 + t * 8]);

    for (int ks = 0; ks < NK; ++ks) {
        __syncthreads();
        if (ks + 1 < NK) {
            const int nb = (ks & 1) ^ 1;
            const int k0 = (ks + 1) * 32;
            gl2lds16(aG + k0,        &sA[nb][t * 8]);
            gl2lds16(aG + k0 + rs64, &sA[nb][2048 + t * 8]);
            gl2lds16(bG + k0,        &sB[nb][t * 8]);
            gl2lds16(bG + k0 + rs64, &sB[nb][2048 + t * 8]);
        }
        const int buf = ks & 1;
        bf16x8 af[4], bfr[4];
#pragma unroll
        for (int m = 0; m < 4; ++m)
            af[m]  = *(const bf16x8*)&sA[buf][(wr * 64 + m * 16 + fr) * 32 + kq * 8];
#pragma unroll
        for (int n = 0; n < 4; ++n)
            bfr[n] = *(const bf16x8*)&sB[buf][(wc * 64 + n * 16 + fr) * 32 + kq * 8];
#pragma unroll
        for (int m = 0; m < 4; ++m)
#pragma unroll
            for (int n = 0; n < 4; ++n)
                acc[m][n] = __builtin_amdgcn_mfma_f32_16x16x32_bf16(
                    af[m], bfr[n], acc[m][n], 0, 0, 0);
    }

#pragma unroll
    for (int n = 0; n < 4; ++n) {
        const int colg = bcol + wc * 64 + n * 16 + fr;
        const float bs = bias[colg];
#pragma unroll
        for (int m = 0; m < 4; ++m) {
            const int rowg = brow + wr * 64 + m * 16 + kq * 4;
#pragma unroll
            for (int j = 0; j < 4; ++j)
                C[(size_t)(rowg + j) * N + colg] = acc[m][n][j] + bs;
        }
    }
}

// ---------------------------------------------------------------------------
// Zero only the border of the padded value image (interior filled by GEMM).
// 393 border pixels/batch * 8 batches * 64 ushort4 = 201,216 elements.
// ---------------------------------------------------------------------------
__global__ __launch_bounds__(256)
void zero_border(unsigned short* __restrict__ p) {
    const int i   = blockIdx.x * 256 + threadIdx.x;
    const int c4  = i & 63;
    const int pix = i >> 6;            // 0 .. 3143
    const int n   = pix / 393;
    const int r   = pix - n * 393;
    int x, y;
    if (r < 201) {                     // full rows y in {0, 65, 66}
        const int q = r / 67;
        y = (q == 0) ? 0 : (q == 1 ? 65 : 66);
        x = r - q * 67;
    } else {                           // y in [1,64], x in {0, 65, 66}
        const int q = r - 201;
        y = 1 + q / 3;
        const int s = q - (q / 3) * 3;
        x = (s == 0) ? 0 : (s == 1 ? 65 : 66);
    }
    const size_t addr = ((size_t)n * PPIX + (size_t)y * PW + x) * DM + c4 * 4;
    *(ushort4*)&p[addr] = make_ushort4(0, 0, 0, 0);
}

// ---------------------------------------------------------------------------
// Weight prep: Wvh bf16 [256][256]; Woh dup-pack bf16 [256][512] = [Wh|Wh];
// Wcath bf16 [128][256] (rows 96-127 zero); bcat fp32 [128].
// ---------------------------------------------------------------------------
__global__ __launch_bounds__(256)
void weight_prep(const float* __restrict__ Wv, const float* __restrict__ Wo,
                 const float* __restrict__ Woff, const float* __restrict__ Wa,
                 const float* __restrict__ boff, const float* __restrict__ ba,
                 unsigned short* __restrict__ Wvh, unsigned short* __restrict__ Woh,
                 unsigned short* __restrict__ Wcath, float* __restrict__ bcat) {
    const int i = blockIdx.x * 256 + threadIdx.x;
    if (i < 65536) {
        Wvh[i] = f2bf(Wv[i]);
    } else if (i < 196608) {
        const int j = i - 65536, n = j >> 9, k = j & 511;
        Woh[j] = f2bf(Wo[n * 256 + (k & 255)]);
    } else if (i < 229376) {
        const int j = i - 196608, n = j >> 8, k = j & 255;
        const float v = (n < 64) ? Woff[n * 256 + k]
                                 : ((n < 96) ? Wa[(n - 64) * 256 + k] : 0.f);
        Wcath[j] = f2bf(v);
    } else if (i < 229504) {
        const int n = i - 229376;
        bcat[n] = (n < 64) ? boff[n] : ((n < 96) ? ba[n - 64] : 0.f);
    }
}

// ---------------------------------------------------------------------------
// Fused softmax + bilinear sampling — one wave per query, branch-free gathers
// from the zero-padded value image; XCD-swizzled so XCD k handles batch k.
// Emits split-bf16 sampled (hi|lo) into SPLIT_S [b][512].
// ---------------------------------------------------------------------------
__device__ __forceinline__ float4 f4axpy(float s, float4 g, float4 a) {
    a.x = fmaf(s, g.x, a.x); a.y = fmaf(s, g.y, a.y);
    a.z = fmaf(s, g.z, a.z); a.w = fmaf(s, g.w, a.w);
    return a;
}
__device__ __forceinline__ float4 bf4_to_f4(ushort4 u) {
    float4 r;
    r.x = bf2f(u.x); r.y = bf2f(u.y); r.z = bf2f(u.z); r.w = bf2f(u.w);
    return r;
}

__global__ __launch_bounds__(256)
void sample_kernel(const float* __restrict__ refp,
                   const unsigned short* __restrict__ valueP,
                   const unsigned short* __restrict__ logitsB,
                   unsigned short* __restrict__ SPLIT_S) {
    const int vb   = (blockIdx.x & 7) * 1024 + (blockIdx.x >> 3);
    const int wid  = threadIdx.x >> 6;
    const int b    = vb * 4 + wid;
    const int n    = b >> 12;
    const int lane = threadIdx.x & 63;

    const int tp  = lane & 31;
    const int pm  = tp >> 2, ppt = tp & 3;
    const unsigned short* lg = logitsB + (size_t)b * LG;

    const float rx = refp[(size_t)b * 2 + 0];
    const float ry = refp[(size_t)b * 2 + 1];
    const float ox = bf2f(lg[pm * 8 + ppt * 2 + 0]);
    const float oy = bf2f(lg[pm * 8 + ppt * 2 + 1]);
    const float la = bf2f(lg[64 + tp]);

    const float x = fminf(fmaxf(fmaf(rx, (float)WW, ox) - 0.5f, -1.0f), 64.0f);
    const float y = fminf(fmaxf(fmaf(ry, (float)HH, oy) - 0.5f, -1.0f), 64.0f);

    float mx = fmaxf(la, __shfl_xor(la, 1));
    mx = fmaxf(mx, __shfl_xor(mx, 2));
    const float e = __expf(la - mx);
    float den = e + __shfl_xor(e, 1);
    den += __shfl_xor(den, 2);
    const float w = e / den;

    const int m  = lane >> 3;
    const int c4 = lane & 7;
    const unsigned short* vbase = valueP + (size_t)n * (PPIX * DM) + m * 32 + c4 * 4;

    float4 acc = make_float4(0.f, 0.f, 0.f, 0.f);
#pragma unroll
    for (int p = 0; p < PP; ++p) {
        const int   sl = m * PP + p;
        const float xp = __shfl(x, sl);
        const float yp = __shfl(y, sl);
        const float wp = __shfl(w, sl);

        const float x0f = floorf(xp), y0f = floorf(yp);
        const int   x0 = (int)x0f,   y0 = (int)y0f;
        const float wx1 = xp - x0f,  wy1 = yp - y0f;
        const float wx0 = 1.f - wx1, wy0 = 1.f - wy1;

        const float w00 = wp * wx0 * wy0, w01 = wp * wx1 * wy0;
        const float w10 = wp * wx0 * wy1, w11 = wp * wx1 * wy1;

        const int idx = (y0 + 1) * PW + (x0 + 1);
        const unsigned short* p00 = vbase + (size_t)idx * DM;

        const ushort4 g00 = *(const ushort4*)(p00);
        const ushort4 g01 = *(const ushort4*)(p00 + DM);
        const ushort4 g10 = *(const ushort4*)(p00 + PW * DM);
        const ushort4 g11 = *(const ushort4*)(p00 + (PW + 1) * DM);

        acc = f4axpy(w00, bf4_to_f4(g00), acc);
        acc = f4axpy(w01, bf4_to_f4(g01), acc);
        acc = f4axpy(w10, bf4_to_f4(g10), acc);
        acc = f4axpy(w11, bf4_to_f4(g11), acc);
    }

    const int ch = m * 32 + c4 * 4;
    ushort4 h, lo;
    h.x = f2bf(acc.x); lo.x = f2bf(acc.x - bf2f(h.x));
    h.y = f2bf(acc.y); lo.y = f2bf(acc.y - bf2f(h.y));
    h.z = f2bf(acc.z); lo.z = f2bf(acc.z - bf2f(h.z));
    h.w = f2bf(acc.w); lo.w = f2bf(acc.w - bf2f(h.w));
    *(ushort4*)&SPLIT_S[(size_t)b * 512 + ch]       = h;
    *(ushort4*)&SPLIT_S[(size_t)b * 512 + 256 + ch] = lo;
}

// ---------------------------------------------------------------------------
extern "C" void kernel_launch(void* const* d_in, const int* in_sizes, int n_in,
                              void* d_out, int out_size, void* d_ws, size_t ws_size,
                              hipStream_t stream) {
    const float* query  = (const float*)d_in[0];   // [8,4096,256]
    const float* refp   = (const float*)d_in[1];   // [8,4096,2]
    const float* inputf = (const float*)d_in[2];   // [8,4096,256]
    const float* Wv   = (const float*)d_in[5];     // [256,256]
    const float* bv   = (const float*)d_in[6];     // [256]
    const float* Woff = (const float*)d_in[7];     // [64,256]
    const float* boff = (const float*)d_in[8];     // [64]
    const float* Wa   = (const float*)d_in[9];     // [32,256]
    const float* ba   = (const float*)d_in[10];    // [32]
    const float* Wo   = (const float*)d_in[11];    // [256,256]
    const float* bo   = (const float*)d_in[12];    // [256]
    float* out = (float*)d_out;

    const int Mrows = NB * LQN;  // 32768

    // workspace layout (ushort units)
    unsigned short* SPLIT_S = (unsigned short*)d_ws;             // 16,777,216
    unsigned short* valueP  = SPLIT_S + (size_t)Mrows * 512;     //  9,193,472
    unsigned short* logitsB = valueP  + (size_t)NB * PPIX * DM;  //  4,194,304
    unsigned short* Wvh     = logitsB + (size_t)Mrows * LG;      //     65,536
    unsigned short* Woh     = Wvh     + 65536;                   //    131,072
    unsigned short* Wcath   = Woh     + 131072;                  //     32,768
    float*          bcat    = (float*)(Wcath + 32768);           //        128

    // 1. weight prep
    weight_prep<<<897, 256, 0, stream>>>(Wv, Wo, Woff, Wa, boff, ba,
                                         Wvh, Woh, Wcath, bcat);

    // 2. zero the padded image border (interior fully written by GEMM)
    zero_border<<<786, 256, 0, stream>>>(valueP);

    // 3. value = input @ Wv^T + bv -> padded bf16 image (hi+lo planes, K=256)
    {
        dim3 g(Mrows / 128, 2);
        gemm_f32a<2, true><<<g, 256, 0, stream>>>(inputf, Wvh, bv, valueP,
                                                  Mrows, DM);
    }

    // 4. logits = query @ Wcat^T + bcat (hi-only, N=128, bf16 out)
    {
        dim3 g(Mrows / 128, 1);
        gemm_f32a<1, false><<<g, 256, 0, stream>>>(query, Wcath, bcat, logitsB,
                                                   Mrows, LG);
    }

    // 5. softmax + bilinear sampling -> SPLIT_S (hi|lo)
    sample_kernel<<<Mrows / 4, 256, 0, stream>>>(refp, valueP, logitsB, SPLIT_S);

    // 6. out = sampled @ Wo^T + bo (fp32 out, K=512 concat)
    {
        dim3 g(Mrows / 128, 2);
        gemm_bf16_nt<<<g, 256, 0, stream>>>(SPLIT_S, Woh, bo, out,
                                            Mrows, DM, 512);
    }
}

// Round 6
// 66.908 us; speedup vs baseline: 4.0687x; 1.1996x over previous
//
#include <hip/hip_runtime.h>
#include <math.h>

// Problem constants (fixed by the reference)
#define NB   8        // batch
#define LQN  4096     // queries
#define DM   256      // d_model
#define MH   8        // heads
#define PP   4        // points
#define HH   64       // H
#define WW   64       // W
#define LG   128      // padded logits row stride (96 real + 32 pad)
#define PW   67       // padded image width/height (x,y in -1..65)
#define PPIX (PW*PW)  // 4489 padded pixels per batch
#define ASTR 40       // LDS A-plane row stride in ushorts (32 + 8 pad -> 80B)

typedef __bf16 bf16x8 __attribute__((ext_vector_type(8)));
typedef float  f32x4  __attribute__((ext_vector_type(4)));
typedef unsigned short us8 __attribute__((ext_vector_type(8)));

__device__ __forceinline__ unsigned short f2bf(float f) {   // RNE fp32 -> bf16 bits
    unsigned u = __float_as_uint(f);
    u += 0x7FFFu + ((u >> 16) & 1u);
    return (unsigned short)(u >> 16);
}
__device__ __forceinline__ float bf2f(unsigned short b) {
    return __uint_as_float((unsigned)b << 16);
}

__device__ __forceinline__ void gl2lds16(const unsigned short* g, unsigned short* l) {
    __builtin_amdgcn_global_load_lds(
        (const __attribute__((address_space(1))) void*)g,
        (__attribute__((address_space(3))) void*)l,
        16, 0, 0);
}

// ---------------------------------------------------------------------------
// Dual fused-convert GEMM (hi-only), one dispatch:
//   blocks [0,512):  value  = input @ Wvh^T + bv  -> scatter into padded image
//   blocks [512,768): logits = query @ Wcath^T + bcat -> [32768][128] bf16
// A fp32 staged global->reg->cvt(bf16)->ds_write; B bf16 via global_load_lds.
// 128x128 tile, BK=32, 256 thr = 4 waves (2x2 of 64x64), double-buffered.
// ---------------------------------------------------------------------------
__global__ __launch_bounds__(256, 2)
void dual_gemm(const float* __restrict__ Ain, const float* __restrict__ Aq,
               const unsigned short* __restrict__ Wvh,
               const unsigned short* __restrict__ Wcath,
               const float* __restrict__ bv, const float* __restrict__ bcat,
               unsigned short* __restrict__ valueP,
               unsigned short* __restrict__ logitsB) {
    constexpr int K = 256;
    __shared__ unsigned short sA[2][128 * ASTR];
    __shared__ unsigned short sB[2][4096];

    const int t    = threadIdx.x;
    const int blk  = blockIdx.x;
    const bool isVal = (blk < 512);

    const float* A; const unsigned short* B; const float* bias;
    int brow, bcol;
    if (isVal) { A = Ain; B = Wvh;   bias = bv;   brow = (blk >> 1) * 128; bcol = (blk & 1) * 128; }
    else       { A = Aq;  B = Wcath; bias = bcat; brow = (blk - 512) * 128; bcol = 0; }

    // A staging: thread t -> row t>>1, 16 cols at (t&1)*16
    const int ar  = t >> 1;
    const int as_ = (t & 1) * 16;
    const float* aG = A + (size_t)(brow + ar) * K + as_;
    const int abase = ar * ASTR + as_;

    // B staging (gl2lds lane-linear): rows t>>2, +64; cols (t&3)*8
    const unsigned short* bG = B + (size_t)(bcol + (t >> 2)) * K + (t & 3) * 8;
    const size_t brs64 = (size_t)64 * K;

    const int l   = t & 63;
    const int wid = t >> 6;
    const int wr  = wid >> 1, wc = wid & 1;
    const int fr  = l & 15,   kq = l >> 4;

    f32x4 acc[4][4] = {};
    float4 va[4];

#define LOAD_A(k0)                                                     \
    {  _Pragma("unroll")                                               \
       for (int j = 0; j < 4; ++j)                                     \
           va[j] = *(const float4*)(aG + (k0) + j * 4); }

#define STAGE_B(buf, k0)                                               \
    {  gl2lds16(bG + (k0),         &sB[buf][t * 8]);                   \
       gl2lds16(bG + (k0) + brs64, &sB[buf][2048 + t * 8]); }

#define STAGE_A(buf)                                                   \
    {  _Pragma("unroll")                                               \
       for (int g = 0; g < 2; ++g) {                                   \
           us8 Hv;                                                     \
           _Pragma("unroll")                                           \
           for (int j = 0; j < 2; ++j) {                               \
               const float4 v = va[g * 2 + j];                         \
               Hv[j*4+0] = f2bf(v.x); Hv[j*4+1] = f2bf(v.y);           \
               Hv[j*4+2] = f2bf(v.z); Hv[j*4+3] = f2bf(v.w);           \
           }                                                           \
           *(us8*)&sA[buf][abase + g * 8] = Hv;                        \
       } }

    LOAD_A(0);
    STAGE_B(0, 0);
    STAGE_A(0);

    for (int ks = 0; ks < K / 32; ++ks) {
        __syncthreads();
        const int cur = ks & 1, nxt = cur ^ 1;
        const bool more = (ks + 1 < K / 32);
        if (more) {
            LOAD_A((ks + 1) * 32);
            STAGE_B(nxt, (ks + 1) * 32);
        }

        bf16x8 ah[4], bf_[4];
#pragma unroll
        for (int m = 0; m < 4; ++m)
            ah[m] = *(const bf16x8*)&sA[cur][(wr * 64 + m * 16 + fr) * ASTR + kq * 8];
#pragma unroll
        for (int n = 0; n < 4; ++n)
            bf_[n] = *(const bf16x8*)&sB[cur][(wc * 64 + n * 16 + fr) * 32 + kq * 8];

#pragma unroll
        for (int m = 0; m < 4; ++m)
#pragma unroll
            for (int n = 0; n < 4; ++n)
                acc[m][n] = __builtin_amdgcn_mfma_f32_16x16x32_bf16(
                    ah[m], bf_[n], acc[m][n], 0, 0, 0);

        if (more) STAGE_A(nxt);
    }
#undef LOAD_A
#undef STAGE_B
#undef STAGE_A

    // epilogue: frag (row = (lane>>4)*4 + j, col = lane&15)
#pragma unroll
    for (int n = 0; n < 4; ++n) {
        const int colg = bcol + wc * 64 + n * 16 + fr;
        const float bs = bias[colg];
#pragma unroll
        for (int m = 0; m < 4; ++m) {
            const int rowg = brow + wr * 64 + m * 16 + kq * 4;
#pragma unroll
            for (int j = 0; j < 4; ++j) {
                const float v = acc[m][n][j] + bs;
                const int row = rowg + j;
                if (isVal) {
                    const int nb_ = row >> 12;
                    const int pix = row & 4095;
                    const int y   = pix >> 6, x = pix & 63;
                    const size_t addr =
                        ((size_t)nb_ * PPIX + (size_t)(y + 1) * PW + (x + 1)) * DM + colg;
                    valueP[addr] = f2bf(v);
                } else {
                    logitsB[(size_t)row * LG + colg] = f2bf(v);
                }
            }
        }
    }
}

// ---------------------------------------------------------------------------
// bf16 NT GEMM (gl2lds staging), fp32 out: out = sampledH @ Woh^T + bo, K=256
// ---------------------------------------------------------------------------
__global__ __launch_bounds__(256, 2)
void gemm_bf16_nt(const unsigned short* __restrict__ A,
                  const unsigned short* __restrict__ B,
                  const float* __restrict__ bias, float* __restrict__ C,
                  int M, int N, int K) {
    __shared__ unsigned short sA[2][4096];
    __shared__ unsigned short sB[2][4096];

    const int t    = threadIdx.x;
    const int brow = blockIdx.x * 128;
    const int bcol = blockIdx.y * 128;

    const unsigned short* aG = A + (size_t)(brow + (t >> 2)) * K + (t & 3) * 8;
    const unsigned short* bG = B + (size_t)(bcol + (t >> 2)) * K + (t & 3) * 8;
    const size_t rs64 = (size_t)64 * K;

    const int l   = t & 63;
    const int wid = t >> 6;
    const int wr  = wid >> 1, wc = wid & 1;
    const int fr  = l & 15,   kq = l >> 4;

    f32x4 acc[4][4] = {};
    const int NK = K / 32;

    gl2lds16(aG,        &sA[0][t * 8]);
    gl2lds16(aG + rs64, &sA[0][2048 + t * 8]);
    gl2lds16(bG,        &sB[0][t * 8]);
    gl2lds16(bG + rs64, &sB[0][2048 + t * 8]);

    for (int ks = 0; ks < NK; ++ks) {
        __syncthreads();
        if (ks + 1 < NK) {
            const int nb = (ks & 1) ^ 1;
            const int k0 = (ks + 1) * 32;
            gl2lds16(aG + k0,        &sA[nb][t * 8]);
            gl2lds16(aG + k0 + rs64, &sA[nb][2048 + t * 8]);
            gl2lds16(bG + k0,        &sB[nb][t * 8]);
            gl2lds16(bG + k0 + rs64, &sB[nb][2048 + t * 8]);
        }
        const int buf = ks & 1;
        bf16x8 af[4], bfr[4];
#pragma unroll
        for (int m = 0; m < 4; ++m)
            af[m]  = *(const bf16x8*)&sA[buf][(wr * 64 + m * 16 + fr) * 32 + kq * 8];
#pragma unroll
        for (int n = 0; n < 4; ++n)
            bfr[n] = *(const bf16x8*)&sB[buf][(wc * 64 + n * 16 + fr) * 32 + kq * 8];
#pragma unroll
        for (int m = 0; m < 4; ++m)
#pragma unroll
            for (int n = 0; n < 4; ++n)
                acc[m][n] = __builtin_amdgcn_mfma_f32_16x16x32_bf16(
                    af[m], bfr[n], acc[m][n], 0, 0, 0);
    }

#pragma unroll
    for (int n = 0; n < 4; ++n) {
        const int colg = bcol + wc * 64 + n * 16 + fr;
        const float bs = bias[colg];
#pragma unroll
        for (int m = 0; m < 4; ++m) {
            const int rowg = brow + wr * 64 + m * 16 + kq * 4;
#pragma unroll
            for (int j = 0; j < 4; ++j)
                C[(size_t)(rowg + j) * N + colg] = acc[m][n][j] + bs;
        }
    }
}

// ---------------------------------------------------------------------------
// Prep: weight bf16 conversion (Wvh, Woh plain [256][256]; Wcath [128][256]
// rows 96-127 zero; bcat fp32[128]) + zero the padded-image border.
// ---------------------------------------------------------------------------
__global__ __launch_bounds__(256)
void prep_kernel(const float* __restrict__ Wv, const float* __restrict__ Wo,
                 const float* __restrict__ Woff, const float* __restrict__ Wa,
                 const float* __restrict__ boff, const float* __restrict__ ba,
                 unsigned short* __restrict__ Wvh, unsigned short* __restrict__ Woh,
                 unsigned short* __restrict__ Wcath, float* __restrict__ bcat,
                 unsigned short* __restrict__ valueP) {
    const int i = blockIdx.x * 256 + threadIdx.x;
    if (i < 65536) {
        Wvh[i] = f2bf(Wv[i]);
    } else if (i < 131072) {
        const int j = i - 65536;
        Woh[j] = f2bf(Wo[j]);
    } else if (i < 163840) {
        const int j = i - 131072, n = j >> 8, k = j & 255;
        const float v = (n < 64) ? Woff[n * 256 + k]
                                 : ((n < 96) ? Wa[(n - 64) * 256 + k] : 0.f);
        Wcath[j] = f2bf(v);
    } else if (i < 163968) {
        const int n = i - 163840;
        bcat[n] = (n < 64) ? boff[n] : ((n < 96) ? ba[n - 64] : 0.f);
    } else if (i < 163968 + 201216) {
        // border pixels: 393 per batch (rows y=0,65,66 full; x in {0,65,66} else)
        const int j   = i - 163968;
        const int c4  = j & 63;
        const int pix = j >> 6;
        const int n   = pix / 393;
        const int r   = pix - n * 393;
        int x, y;
        if (r < 201) {
            const int q = r / 67;
            y = (q == 0) ? 0 : (q == 1 ? 65 : 66);
            x = r - q * 67;
        } else {
            const int q = r - 201;
            y = 1 + q / 3;
            const int s = q - (q / 3) * 3;
            x = (s == 0) ? 0 : (s == 1 ? 65 : 66);
        }
        const size_t addr = ((size_t)n * PPIX + (size_t)y * PW + x) * DM + c4 * 4;
        *(ushort4*)&valueP[addr] = make_ushort4(0, 0, 0, 0);
    }
}

// ---------------------------------------------------------------------------
// Fused softmax + bilinear sampling — one wave per query.
// Wave split: half = lane>>5 owns y-corner (y0+half); c8 = lane&31 owns
// channels [c8*8, +8). Per point: two 16B gathers (x0, x0+1); halves combined
// via shfl_xor(32). Branch-free via zero-padded image + clamp. XCD-swizzled
// (batch k -> XCD k). Output: plain bf16 sampledH [32768][256].
// ---------------------------------------------------------------------------
__global__ __launch_bounds__(256)
void sample_kernel(const float* __restrict__ refp,
                   const unsigned short* __restrict__ valueP,
                   const unsigned short* __restrict__ logitsB,
                   unsigned short* __restrict__ sampledH) {
    const int vb   = (blockIdx.x & 7) * 1024 + (blockIdx.x >> 3);
    const int wid  = threadIdx.x >> 6;
    const int b    = vb * 4 + wid;
    const int n    = b >> 12;
    const int lane = threadIdx.x & 63;

    // ---- point setup on tp = lane&31 (replicated in both halves) ----
    const int tp  = lane & 31;
    const int pm  = tp >> 2, ppt = tp & 3;
    const unsigned short* lg = logitsB + (size_t)b * LG;

    const float rx = refp[(size_t)b * 2 + 0];
    const float ry = refp[(size_t)b * 2 + 1];
    const float ox = bf2f(lg[pm * 8 + ppt * 2 + 0]);
    const float oy = bf2f(lg[pm * 8 + ppt * 2 + 1]);
    const float la = bf2f(lg[64 + tp]);

    const float x = fminf(fmaxf(fmaf(rx, (float)WW, ox) - 0.5f, -1.0f), 64.0f);
    const float y = fminf(fmaxf(fmaf(ry, (float)HH, oy) - 0.5f, -1.0f), 64.0f);

    float mx = fmaxf(la, __shfl_xor(la, 1));
    mx = fmaxf(mx, __shfl_xor(mx, 2));
    const float e = __expf(la - mx);
    float den = e + __shfl_xor(e, 1);
    den += __shfl_xor(den, 2);
    const float w = e / den;

    // ---- gather ----
    const int half = lane >> 5;          // which y-corner this half handles
    const int c8   = lane & 31;          // channel octet: channels [c8*8, +8)
    const int mh   = c8 >> 2;            // head of these channels
    const unsigned short* vbase = valueP + (size_t)n * (PPIX * DM) + c8 * 8;

    float accv[8] = {};
#pragma unroll
    for (int p = 0; p < PP; ++p) {
        const int   sl = mh * PP + p;
        const float xp = __shfl(x, sl);
        const float yp = __shfl(y, sl);
        const float wp = __shfl(w, sl);

        const float x0f = floorf(xp), y0f = floorf(yp);
        const int   x0 = (int)x0f,   y0 = (int)y0f;
        const float wx1 = xp - x0f,  wy1 = yp - y0f;
        const float wy  = half ? wy1 : (1.f - wy1);
        const float wA  = wp * wy * (1.f - wx1);
        const float wB  = wp * wy * wx1;

        const unsigned short* p0 =
            vbase + (size_t)((y0 + 1 + half) * PW + (x0 + 1)) * DM;
        const us8 gA = *(const us8*)(p0);
        const us8 gB = *(const us8*)(p0 + DM);
#pragma unroll
        for (int j = 0; j < 8; ++j) {
            accv[j] = fmaf(wA, bf2f(gA[j]), accv[j]);
            accv[j] = fmaf(wB, bf2f(gB[j]), accv[j]);
        }
    }

    // combine the two y-corner halves
#pragma unroll
    for (int j = 0; j < 8; ++j)
        accv[j] += __shfl_xor(accv[j], 32);

    if (half == 0) {
        us8 o;
#pragma unroll
        for (int j = 0; j < 8; ++j) o[j] = f2bf(accv[j]);
        *(us8*)&sampledH[(size_t)b * DM + c8 * 8] = o;
    }
}

// ---------------------------------------------------------------------------
extern "C" void kernel_launch(void* const* d_in, const int* in_sizes, int n_in,
                              void* d_out, int out_size, void* d_ws, size_t ws_size,
                              hipStream_t stream) {
    const float* query  = (const float*)d_in[0];   // [8,4096,256]
    const float* refp   = (const float*)d_in[1];   // [8,4096,2]
    const float* inputf = (const float*)d_in[2];   // [8,4096,256]
    const float* Wv   = (const float*)d_in[5];     // [256,256]
    const float* bv   = (const float*)d_in[6];     // [256]
    const float* Woff = (const float*)d_in[7];     // [64,256]
    const float* boff = (const float*)d_in[8];     // [64]
    const float* Wa   = (const float*)d_in[9];     // [32,256]
    const float* ba   = (const float*)d_in[10];    // [32]
    const float* Wo   = (const float*)d_in[11];    // [256,256]
    const float* bo   = (const float*)d_in[12];    // [256]
    float* out = (float*)d_out;

    const int Mrows = NB * LQN;  // 32768

    // workspace layout (ushort units)
    unsigned short* sampledH = (unsigned short*)d_ws;              //  8,388,608
    unsigned short* valueP   = sampledH + (size_t)Mrows * DM;      //  9,193,472
    unsigned short* logitsB  = valueP   + (size_t)NB * PPIX * DM;  //  4,194,304
    unsigned short* Wvh      = logitsB  + (size_t)Mrows * LG;      //     65,536
    unsigned short* Woh      = Wvh      + 65536;                   //     65,536
    unsigned short* Wcath    = Woh      + 65536;                   //     32,768
    float*          bcat     = (float*)(Wcath + 32768);            //        128

    // 1. prep: weight bf16 conversion + image border zero
    prep_kernel<<<1427, 256, 0, stream>>>(Wv, Wo, Woff, Wa, boff, ba,
                                          Wvh, Woh, Wcath, bcat, valueP);

    // 2. fused dual GEMM: value (scatter into padded image) + logits
    dual_gemm<<<768, 256, 0, stream>>>(inputf, query, Wvh, Wcath, bv, bcat,
                                       valueP, logitsB);

    // 3. softmax + bilinear sampling -> sampledH (bf16)
    sample_kernel<<<Mrows / 4, 256, 0, stream>>>(refp, valueP, logitsB, sampledH);

    // 4. out = sampled @ Wo^T + bo (fp32 out, K=256)
    {
        dim3 g(Mrows / 128, 2);
        gemm_bf16_nt<<<g, 256, 0, stream>>>(sampledH, Woh, bo, out,
                                            Mrows, DM, 256);
    }
}